// Round 15
// baseline (190.736 us; speedup 1.0000x reference)
//
#include <hip/hip_runtime.h>
#include <stdint.h>

// RBF kernel attention, MI355X. N=4, L=S=2048, H=8, E=D=64.
// phi = exp(-(q^2+k^2-2qk)/16)*mask; out = (phi V)/(rowsum(phi)+1e-6)
// Factorized: p = exp2(fma(C1, qk, lb)), lb = -C2*k^2 + log2(mask); q^2
// cancels in Z; epilogue eps' = 1e-6*exp2(C2*q^2).
// Round-15 = r14 champion + V moved OFF the LDS pipe:
//   - K double-buffered in LDS (16.6KB); V^T fragments loaded directly
//     from global (L2-resident via XCD swizzle) into registers.
//   - r6's failure fixed by ISSUE ORDER: V(i+1) loads issue at the END of
//     chunk i BEFORE SK(i+2), so PV(i+1) consumes V at vmcnt(2) and the
//     K-staging prefetch is never drained (r6 had V newest -> vmcnt(0)).
//   - steady head wait vmcnt(14): completes exactly SK(i) out of
//     {SK(i)2, LB(i)4, V(i)8, SK(i+1)2}; loop never drains to 0.
//   - single-set lb and V registers (WAR-ordered); ~95 VGPR, (256,2).
// LDS traffic/CU halves (8.4 -> 4.2 MB); V 4.2MB rides the idle L2 pipe.
//
// ws layout:
//   [0,8MB)    K bf16   [n][h][s][64]
//   [8,16MB)   V^T bf16 [n][h][d][sigma(s)]
//   [16MB,+256KB) lbf f32 [n][h][s]

#define N_ 4
#define L_ 2048
#define H_ 8
#define S_ 2048

#define C1 0.18033688f   // log2(e)/8
#define C2 0.09016844f   // log2(e)/16

typedef unsigned short ushort_t;
typedef unsigned int uint_t;
typedef __bf16 b8 __attribute__((ext_vector_type(8)));
typedef float f4 __attribute__((ext_vector_type(4)));
typedef const __attribute__((address_space(1))) uint32_t* gas_ptr;
typedef __attribute__((address_space(3))) uint32_t* las_ptr;

static __device__ __forceinline__ ushort_t f2bf(float x) {
  uint32_t u = __float_as_uint(x);
  u += 0x7fffu + ((u >> 16) & 1u);   // RNE
  return (ushort_t)(u >> 16);
}

// Merged prepass. Blocks 0-1023: K fp32 -> bf16 + lbf. Blocks 1024-2047:
// V [n][s][h][64] fp32 -> V^T bf16 [n][h][d][sigma(s)] via LDS tile.
// sigma: stored position p holds source s=(p&32)+((p>>2)&1)*16+((p>>3)&3)*4+(p&3)
// so the PV B-fragment (keys 32sst+4g+16(b>>2)+(b&3)) is one contiguous b128.
__global__ __launch_bounds__(256) void k_prep(const float* __restrict__ ksrc,
                                              ushort_t* __restrict__ kdst,
                                              float* __restrict__ lbf,
                                              const float* __restrict__ mask,
                                              const float* __restrict__ v,
                                              ushort_t* __restrict__ vt) {
  __shared__ __align__(16) ushort_t tile[64][68];
  if (blockIdx.x < 1024) {
    // ---- K convert + lb ----
    int t = blockIdx.x * 256 + threadIdx.x;
    int row = t >> 2, part = t & 3;
    const float4* p = reinterpret_cast<const float4*>(ksrc + (size_t)row * 64 + part * 16);
    uint_t o[8];
    float s = 0.f;
#pragma unroll
    for (int i = 0; i < 4; ++i) {
      float4 vv = p[i];
      s += vv.x * vv.x + vv.y * vv.y + vv.z * vv.z + vv.w * vv.w;
      o[2 * i]     = (uint_t)f2bf(vv.x) | ((uint_t)f2bf(vv.y) << 16);
      o[2 * i + 1] = (uint_t)f2bf(vv.z) | ((uint_t)f2bf(vv.w) << 16);
    }
    uint4* dp = reinterpret_cast<uint4*>(kdst + (size_t)row * 64 + part * 16);
    dp[0] = make_uint4(o[0], o[1], o[2], o[3]);
    dp[1] = make_uint4(o[4], o[5], o[6], o[7]);
    s += __shfl_xor(s, 1);
    s += __shfl_xor(s, 2);
    if (part == 0) {
      int n = row >> 14;          // / (H*S)
      int sidx = row & (S_ - 1);  // % S
      float m = mask[n * S_ + sidx];
      lbf[row] = -C2 * s + __log2f(m);   // m=0 -> -inf -> p=0
    }
  } else {
    // ---- V transpose ----
    const int vb = blockIdx.x - 1024;
    const int sc = vb & 31;
    const int h = (vb >> 5) & 7;
    const int n = vb >> 8;
    const int t = threadIdx.x;
    const int sl = t >> 4;
    const int dp = (t & 15) * 4;
#pragma unroll
    for (int i = 0; i < 4; ++i) {
      int s = sc * 64 + i * 16 + sl;
      float4 val = *reinterpret_cast<const float4*>(
          v + (((size_t)n * S_ + s) * H_ + h) * 64 + dp);
      tile[dp + 0][i * 16 + sl] = f2bf(val.x);
      tile[dp + 1][i * 16 + sl] = f2bf(val.y);
      tile[dp + 2][i * 16 + sl] = f2bf(val.z);
      tile[dp + 3][i * 16 + sl] = f2bf(val.w);
    }
    __syncthreads();
    const int d = t >> 2, sp = (t & 3) * 16;
    uint_t o[8];
#pragma unroll
    for (int i = 0; i < 8; ++i) {
      const int p0 = sp + 2 * i, p1 = p0 + 1;
      const int s0 = (p0 & 32) + (((p0 >> 2) & 1) << 4) + (((p0 >> 3) & 3) << 2) + (p0 & 3);
      const int s1 = (p1 & 32) + (((p1 >> 2) & 1) << 4) + (((p1 >> 3) & 3) << 2) + (p1 & 3);
      o[i] = (uint_t)tile[d][s0] | ((uint_t)tile[d][s1] << 16);
    }
    size_t base = ((size_t)(n * H_ + h) * 64 + d) * S_ + sc * 64 + sp;
    uint4* w = reinterpret_cast<uint4*>(vt + base);
    w[0] = make_uint4(o[0], o[1], o[2], o[3]);
    w[1] = make_uint4(o[4], o[5], o[6], o[7]);
  }
}

// Main kernel: 4 waves/block, wave owns 16 q-rows, chunk = 64 keys.
// K dbuf in LDS; V^T direct-to-registers (issued end of prev chunk).
__global__ __launch_bounds__(256, 2) void k_attn(
    const float* __restrict__ qf32, const ushort_t* __restrict__ kb,
    const ushort_t* __restrict__ vt, const float* __restrict__ lbf,
    float* __restrict__ out) {
  __shared__ __align__(16) ushort_t kt[2][64 * 64];
  __shared__ __align__(16) float zb[4][16];

  const int lane = threadIdx.x & 63;
  const int w = threadIdx.x >> 6;   // 0..3
  const int bid = blockIdx.x;
  const int swz = (bid & 7) * 128 + (bid >> 3);  // XCD-chunked (1024 % 8 == 0)
  const int qt = swz & 31;
  const int hd = (swz >> 5) & 7;
  const int n = swz >> 8;
  const int nh = n * H_ + hd;
  const int c = lane & 15;
  const int g = lane >> 4;
  const int qrow0 = qt * 64 + w * 16;

  union U4 { uint_t u[4]; b8 v; };

  // ---- Q prologue: fp32 -> bf16 frags + q^2 -> eps' ----
  const float* qsrc = qf32 + ((size_t)nh * L_ + qrow0) * 64;
  b8 qfr[2];
  float epsr;
  {
    const float* rp = qsrc + (size_t)c * 64 + g * 8;
    float s = 0.f;
#pragma unroll
    for (int es = 0; es < 2; ++es) {
      float4 v0 = *reinterpret_cast<const float4*>(rp + es * 32);
      float4 v1 = *reinterpret_cast<const float4*>(rp + es * 32 + 4);
      s += v0.x * v0.x + v0.y * v0.y + v0.z * v0.z + v0.w * v0.w
         + v1.x * v1.x + v1.y * v1.y + v1.z * v1.z + v1.w * v1.w;
      U4 tq;
      tq.u[0] = (uint_t)f2bf(v0.x) | ((uint_t)f2bf(v0.y) << 16);
      tq.u[1] = (uint_t)f2bf(v0.z) | ((uint_t)f2bf(v0.w) << 16);
      tq.u[2] = (uint_t)f2bf(v1.x) | ((uint_t)f2bf(v1.y) << 16);
      tq.u[3] = (uint_t)f2bf(v1.z) | ((uint_t)f2bf(v1.w) << 16);
      qfr[es] = tq.v;
    }
    s += __shfl_xor(s, 16);
    s += __shfl_xor(s, 32);
    epsr = 1e-6f * exp2f(C2 * s);   // eps' for q-row c
  }

  const ushort_t* kbh = kb + (size_t)nh * S_ * 64;
  const ushort_t* vth = vt + (size_t)nh * 64 * S_;
  const float* lbh = lbf + (size_t)nh * S_;

  f4 zero4 = {0.f, 0.f, 0.f, 0.f};
  f4 acc[4] = {zero4, zero4, zero4, zero4};
  float rs = 0.f;

  const int lrow = lane >> 3;          // staging row in 8-row piece
  const int lc16 = (lane & 7) ^ lrow;  // pre-swizzled global 16B slot

  float4 lbv[4];    // lb for current chunk (single set, WAR-ordered reload)
  b8 vf[8];         // V frags for current chunk: [sst*4+db] (single set)

  // V^T row base pointers: row db*16 + c, element offset g*8 (+32 for sst=1)
  const ushort_t* vp0 = vth + (size_t)(0 * 16 + c) * S_ + g * 8;
  const ushort_t* vp1 = vth + (size_t)(1 * 16 + c) * S_ + g * 8;
  const ushort_t* vp2 = vth + (size_t)(2 * 16 + c) * S_ + g * 8;
  const ushort_t* vp3 = vth + (size_t)(3 * 16 + c) * S_ + g * 8;

#define WAITV14 asm volatile("s_waitcnt vmcnt(14)" ::: "memory")
#define WAITV12 asm volatile("s_waitcnt vmcnt(12)" ::: "memory")

// K-only staging: 2 global_load_lds per wave per chunk.
#define STAGE(bufi, ch)                                                        \
  {                                                                            \
    _Pragma("unroll")                                                          \
    for (int t2 = 0; t2 < 2; ++t2) {                                           \
      const int rr = w * 16 + t2 * 8;                                          \
      const ushort_t* gk = kbh + ((size_t)(ch) * 64 + rr + lrow) * 64 + lc16 * 8; \
      __builtin_amdgcn_global_load_lds((gas_ptr)gk, (las_ptr)(&kt[bufi][rr * 64]), 16, 0, 0); \
    }                                                                          \
  }

#define LBLOAD(ch)                                                             \
  {                                                                            \
    _Pragma("unroll")                                                          \
    for (int ss = 0; ss < 4; ++ss)                                             \
      lbv[ss] = *reinterpret_cast<const float4*>(lbh + (ch) * 64 + ss * 16 + 4 * g); \
  }

// V fragments for chunk ch -> vf[8] (8 x global_load_dwordx4, L2-hit).
#define VLOAD(ch)                                                              \
  {                                                                            \
    vf[0] = *reinterpret_cast<const b8*>(vp0 + (ch) * 64);                     \
    vf[1] = *reinterpret_cast<const b8*>(vp1 + (ch) * 64);                     \
    vf[2] = *reinterpret_cast<const b8*>(vp2 + (ch) * 64);                     \
    vf[3] = *reinterpret_cast<const b8*>(vp3 + (ch) * 64);                     \
    vf[4] = *reinterpret_cast<const b8*>(vp0 + (ch) * 64 + 32);                \
    vf[5] = *reinterpret_cast<const b8*>(vp1 + (ch) * 64 + 32);                \
    vf[6] = *reinterpret_cast<const b8*>(vp2 + (ch) * 64 + 32);                \
    vf[7] = *reinterpret_cast<const b8*>(vp3 + (ch) * 64 + 32);                \
  }

// One 64-key chunk. WAITX completes SK(CH) (LB/V for this chunk finished by
// compiler-inserted counted waits; SK(CH+1) stays in flight).
#define CHUNK(CH, BUF, DO_LB, DO_S, WAITX)                                     \
  {                                                                            \
    WAITX;                                                                     \
    __builtin_amdgcn_s_barrier();                                              \
    __builtin_amdgcn_sched_barrier(0);                                         \
    uint_t pw[8];                                                              \
    _Pragma("unroll")                                                          \
    for (int ss = 0; ss < 4; ++ss) {                                           \
      const ushort_t* ktb = &kt[BUF][(ss * 16 + c) * 64];                      \
      b8 ak0 = *reinterpret_cast<const b8*>(ktb + (g ^ (c & 7)) * 8);          \
      b8 ak1 = *reinterpret_cast<const b8*>(ktb + ((4 + g) ^ (c & 7)) * 8);    \
      __builtin_amdgcn_s_setprio(1);                                           \
      f4 s0 = __builtin_amdgcn_mfma_f32_16x16x32_bf16(ak0, qfr[0], zero4, 0, 0, 0); \
      s0 = __builtin_amdgcn_mfma_f32_16x16x32_bf16(ak1, qfr[1], s0, 0, 0, 0);  \
      __builtin_amdgcn_s_setprio(0);                                           \
      float p0 = exp2f(fmaf(C1, s0[0], lbv[ss].x));                            \
      float p1 = exp2f(fmaf(C1, s0[1], lbv[ss].y));                            \
      float p2 = exp2f(fmaf(C1, s0[2], lbv[ss].z));                            \
      float p3 = exp2f(fmaf(C1, s0[3], lbv[ss].w));                            \
      rs += (p0 + p1) + (p2 + p3);                                             \
      asm("v_cvt_pk_bf16_f32 %0, %1, %2" : "=v"(pw[2 * ss])     : "v"(p0), "v"(p1)); \
      asm("v_cvt_pk_bf16_f32 %0, %1, %2" : "=v"(pw[2 * ss + 1]) : "v"(p2), "v"(p3)); \
    }                                                                          \
    __builtin_amdgcn_s_setprio(1);                                             \
    _Pragma("unroll")                                                          \
    for (int sst = 0; sst < 2; ++sst) {                                        \
      U4 pa;                                                                   \
      pa.u[0] = pw[4 * sst + 0]; pa.u[1] = pw[4 * sst + 1];                    \
      pa.u[2] = pw[4 * sst + 2]; pa.u[3] = pw[4 * sst + 3];                    \
      _Pragma("unroll")                                                        \
      for (int db = 0; db < 4; ++db) {                                         \
        acc[db] = __builtin_amdgcn_mfma_f32_16x16x32_bf16(pa.v, vf[4 * sst + db], acc[db], 0, 0, 0); \
      }                                                                        \
    }                                                                          \
    __builtin_amdgcn_s_setprio(0);                                             \
    __builtin_amdgcn_sched_barrier(0);                                         \
    __builtin_amdgcn_s_barrier();                                              \
    if (DO_LB) { LBLOAD((CH) + 1); VLOAD((CH) + 1); }                          \
    __builtin_amdgcn_sched_barrier(0);                                         \
    if (DO_S) { STAGE(BUF, (CH) + 2); }                                        \
  }

  // Prologue: SK(0)[2], LB(0)[4], V(0)[8], SK(1)[2] -> 16 vmem in flight.
  STAGE(0, 0);
  LBLOAD(0);
  VLOAD(0);
  __builtin_amdgcn_sched_barrier(0);
  STAGE(1, 1);

  for (int ch = 0; ch < 28; ch += 2) {
    CHUNK(ch,     0, true, true, WAITV14);
    CHUNK(ch + 1, 1, true, true, WAITV14);
  }
  CHUNK(28, 0, true,  true,  WAITV14);   // LB/V(29), SK(30)
  CHUNK(29, 1, true,  true,  WAITV14);   // LB/V(30), SK(31)
  CHUNK(30, 0, true,  false, WAITV14);   // LB/V(31)
  CHUNK(31, 1, false, false, WAITV12);   // completes SK(31); LB/V via compiler

#undef CHUNK
#undef STAGE
#undef LBLOAD
#undef VLOAD
#undef WAITV14
#undef WAITV12

  // Z per q-row: lane (c,g) rs = partial for q-row c; reduce over g.
  rs += __shfl_xor(rs, 16);
  rs += __shfl_xor(rs, 32);
  if (g == 0) zb[w][c] = 1.f / (rs + epsr);
  __syncthreads();

  // out[n][qrow0 + 4g + r][hd][db*16 + c]
  const float4 z4 = *reinterpret_cast<const float4*>(&zb[w][4 * g]);
  const float zz[4] = {z4.x, z4.y, z4.z, z4.w};
  float* ob = out + (((size_t)n * L_ + qrow0 + 4 * g) * H_ + hd) * 64;
#pragma unroll
  for (int db = 0; db < 4; ++db) {
#pragma unroll
    for (int r = 0; r < 4; ++r) {
      ob[(size_t)r * (H_ * 64) + db * 16 + c] = acc[db][r] * zz[r];
    }
  }
}

extern "C" void kernel_launch(void* const* d_in, const int* in_sizes, int n_in,
                              void* d_out, int out_size, void* d_ws, size_t ws_size,
                              hipStream_t stream) {
  const float* q = (const float*)d_in[0];
  const float* k = (const float*)d_in[1];
  const float* v = (const float*)d_in[2];
  const float* mask = (const float*)d_in[3];
  float* out = (float*)d_out;

  char* ws = (char*)d_ws;
  ushort_t* kb = (ushort_t*)ws;
  ushort_t* vt = (ushort_t*)(ws + ((size_t)8 << 20));
  float* lbf = (float*)(ws + ((size_t)16 << 20));

  k_prep<<<dim3(2048), dim3(256), 0, stream>>>(k, kb, lbf, mask, v, vt);
  k_attn<<<dim3(1024), dim3(256), 0, stream>>>(q, kb, vt, lbf, out);
}

// Round 16
// 77.336 us; speedup vs baseline: 2.4663x; 2.4663x over previous
//
#include <hip/hip_runtime.h>
#include <stdint.h>

// RBF kernel attention, MI355X. N=4, L=S=2048, H=8, E=D=64.
// phi = exp(-(q^2+k^2-2qk)/16)*mask; out = (phi V)/(rowsum(phi)+1e-6)
// Factorized: p = exp2(fma(C1, qk, lb)), lb = -C2*k^2 + log2(mask); q^2
// cancels in Z; epilogue eps' = 1e-6*exp2(C2*q^2).
// FINAL (r14 champion, restored after r15's V-from-global regression):
//   k_attn: 16 q-rows/wave, 4-wave blocks, grid 1024 (= 4 blocks/CU =
//   4 waves/SIMD), 64-key chunks, K+V double-buffered in LDS via
//   global_load_lds (pre-swizzled source), counted-vmcnt pipeline
//   (vmcnt(8) at chunk head, never drained in-loop), swapped QK^T with
//   zero-shuffle PV (V^T column-permuted in prepass), XCD-chunked swizzle.
//   k_prep: merged K-convert+lb and V-transpose prepass (one launch).
// Closed routes (measured): V direct-from-global (r6/r15: ~185us, page-
// scattered gathers); 32x32 MFMA (r3: 4.2M bank conflicts); 32q/wave
// variants (r8/r10/r11/r13: occupancy geometry); split-K (r13 spin-merge,
// r9/r12 launch-bounds spill).
//
// ws layout:
//   [0,8MB)    K bf16   [n][h][s][64]
//   [8,16MB)   V^T bf16 [n][h][d][sigma(s)]
//   [16MB,+256KB) lbf f32 [n][h][s]

#define N_ 4
#define L_ 2048
#define H_ 8
#define S_ 2048

#define C1 0.18033688f   // log2(e)/8
#define C2 0.09016844f   // log2(e)/16

typedef unsigned short ushort_t;
typedef unsigned int uint_t;
typedef __bf16 b8 __attribute__((ext_vector_type(8)));
typedef float f4 __attribute__((ext_vector_type(4)));
typedef const __attribute__((address_space(1))) uint32_t* gas_ptr;
typedef __attribute__((address_space(3))) uint32_t* las_ptr;

static __device__ __forceinline__ ushort_t f2bf(float x) {
  uint32_t u = __float_as_uint(x);
  u += 0x7fffu + ((u >> 16) & 1u);   // RNE
  return (ushort_t)(u >> 16);
}

// Merged prepass. Blocks 0-1023: K fp32 -> bf16 + lbf. Blocks 1024-2047:
// V [n][s][h][64] fp32 -> V^T bf16 [n][h][d][sigma(s)] via LDS tile.
// sigma: stored position p holds source s=(p&32)+((p>>2)&1)*16+((p>>3)&3)*4+(p&3)
// so the PV B-fragment (keys 32sst+4g+16(b>>2)+(b&3)) is one contiguous b128.
__global__ __launch_bounds__(256) void k_prep(const float* __restrict__ ksrc,
                                              ushort_t* __restrict__ kdst,
                                              float* __restrict__ lbf,
                                              const float* __restrict__ mask,
                                              const float* __restrict__ v,
                                              ushort_t* __restrict__ vt) {
  __shared__ __align__(16) ushort_t tile[64][68];
  if (blockIdx.x < 1024) {
    // ---- K convert + lb ----
    int t = blockIdx.x * 256 + threadIdx.x;
    int row = t >> 2, part = t & 3;
    const float4* p = reinterpret_cast<const float4*>(ksrc + (size_t)row * 64 + part * 16);
    uint_t o[8];
    float s = 0.f;
#pragma unroll
    for (int i = 0; i < 4; ++i) {
      float4 vv = p[i];
      s += vv.x * vv.x + vv.y * vv.y + vv.z * vv.z + vv.w * vv.w;
      o[2 * i]     = (uint_t)f2bf(vv.x) | ((uint_t)f2bf(vv.y) << 16);
      o[2 * i + 1] = (uint_t)f2bf(vv.z) | ((uint_t)f2bf(vv.w) << 16);
    }
    uint4* dp = reinterpret_cast<uint4*>(kdst + (size_t)row * 64 + part * 16);
    dp[0] = make_uint4(o[0], o[1], o[2], o[3]);
    dp[1] = make_uint4(o[4], o[5], o[6], o[7]);
    s += __shfl_xor(s, 1);
    s += __shfl_xor(s, 2);
    if (part == 0) {
      int n = row >> 14;          // / (H*S)
      int sidx = row & (S_ - 1);  // % S
      float m = mask[n * S_ + sidx];
      lbf[row] = -C2 * s + __log2f(m);   // m=0 -> -inf -> p=0
    }
  } else {
    // ---- V transpose ----
    const int vb = blockIdx.x - 1024;
    const int sc = vb & 31;          // 32 s-chunks
    const int h = (vb >> 5) & 7;
    const int n = vb >> 8;
    const int t = threadIdx.x;
    const int sl = t >> 4;
    const int dp = (t & 15) * 4;
#pragma unroll
    for (int i = 0; i < 4; ++i) {
      int s = sc * 64 + i * 16 + sl;
      float4 val = *reinterpret_cast<const float4*>(
          v + (((size_t)n * S_ + s) * H_ + h) * 64 + dp);
      tile[dp + 0][i * 16 + sl] = f2bf(val.x);
      tile[dp + 1][i * 16 + sl] = f2bf(val.y);
      tile[dp + 2][i * 16 + sl] = f2bf(val.z);
      tile[dp + 3][i * 16 + sl] = f2bf(val.w);
    }
    __syncthreads();
    const int d = t >> 2, sp = (t & 3) * 16;
    uint_t o[8];
#pragma unroll
    for (int i = 0; i < 8; ++i) {
      const int p0 = sp + 2 * i, p1 = p0 + 1;
      const int s0 = (p0 & 32) + (((p0 >> 2) & 1) << 4) + (((p0 >> 3) & 3) << 2) + (p0 & 3);
      const int s1 = (p1 & 32) + (((p1 >> 2) & 1) << 4) + (((p1 >> 3) & 3) << 2) + (p1 & 3);
      o[i] = (uint_t)tile[d][s0] | ((uint_t)tile[d][s1] << 16);
    }
    size_t base = ((size_t)(n * H_ + h) * 64 + d) * S_ + sc * 64 + sp;
    uint4* w = reinterpret_cast<uint4*>(vt + base);
    w[0] = make_uint4(o[0], o[1], o[2], o[3]);
    w[1] = make_uint4(o[4], o[5], o[6], o[7]);
  }
}

// Main kernel (champion): 4 waves/block, wave owns 16 q-rows, chunk = 64
// keys, counted-vmcnt double-buffered pipeline.
__global__ __launch_bounds__(256, 4) void k_attn(
    const float* __restrict__ qf32, const ushort_t* __restrict__ kb,
    const ushort_t* __restrict__ vt, const float* __restrict__ lbf,
    float* __restrict__ out) {
  __shared__ __align__(16) ushort_t kt[2][64 * 64];
  __shared__ __align__(16) ushort_t vtt[2][64 * 64];
  __shared__ __align__(16) float zb[4][16];

  const int lane = threadIdx.x & 63;
  const int w = threadIdx.x >> 6;   // 0..3
  const int bid = blockIdx.x;
  const int swz = (bid & 7) * 128 + (bid >> 3);  // XCD-chunked (1024 % 8 == 0)
  const int qt = swz & 31;
  const int hd = (swz >> 5) & 7;
  const int n = swz >> 8;
  const int nh = n * H_ + hd;
  const int c = lane & 15;
  const int g = lane >> 4;
  const int qrow0 = qt * 64 + w * 16;

  union U4 { uint_t u[4]; b8 v; };

  // ---- Q prologue: fp32 -> bf16 frags + q^2 -> eps' ----
  const float* qsrc = qf32 + ((size_t)nh * L_ + qrow0) * 64;
  b8 qfr[2];
  float epsr;
  {
    const float* rp = qsrc + (size_t)c * 64 + g * 8;
    float s = 0.f;
#pragma unroll
    for (int es = 0; es < 2; ++es) {
      float4 v0 = *reinterpret_cast<const float4*>(rp + es * 32);
      float4 v1 = *reinterpret_cast<const float4*>(rp + es * 32 + 4);
      s += v0.x * v0.x + v0.y * v0.y + v0.z * v0.z + v0.w * v0.w
         + v1.x * v1.x + v1.y * v1.y + v1.z * v1.z + v1.w * v1.w;
      U4 tq;
      tq.u[0] = (uint_t)f2bf(v0.x) | ((uint_t)f2bf(v0.y) << 16);
      tq.u[1] = (uint_t)f2bf(v0.z) | ((uint_t)f2bf(v0.w) << 16);
      tq.u[2] = (uint_t)f2bf(v1.x) | ((uint_t)f2bf(v1.y) << 16);
      tq.u[3] = (uint_t)f2bf(v1.z) | ((uint_t)f2bf(v1.w) << 16);
      qfr[es] = tq.v;
    }
    s += __shfl_xor(s, 16);
    s += __shfl_xor(s, 32);
    epsr = 1e-6f * exp2f(C2 * s);   // eps' for q-row c
  }

  const ushort_t* kbh = kb + (size_t)nh * S_ * 64;
  const ushort_t* vth = vt + (size_t)nh * 64 * S_;
  const float* lbh = lbf + (size_t)nh * S_;

  f4 zero4 = {0.f, 0.f, 0.f, 0.f};
  f4 acc[4] = {zero4, zero4, zero4, zero4};
  float rs = 0.f;

  const int lrow = lane >> 3;          // staging row in 8-row piece
  const int lc16 = (lane & 7) ^ lrow;  // pre-swizzled global 16B slot

  float4 lbA[4], lbB[4];

#define WAITV8 asm volatile("s_waitcnt vmcnt(8)" ::: "memory")
#define WAITV4 asm volatile("s_waitcnt vmcnt(4)" ::: "memory")

#define STAGE(bufi, ch)                                                        \
  {                                                                            \
    _Pragma("unroll")                                                          \
    for (int t2 = 0; t2 < 2; ++t2) {                                           \
      const int rr = w * 16 + t2 * 8;                                          \
      const ushort_t* gk = kbh + ((size_t)(ch) * 64 + rr + lrow) * 64 + lc16 * 8; \
      __builtin_amdgcn_global_load_lds((gas_ptr)gk, (las_ptr)(&kt[bufi][rr * 64]), 16, 0, 0); \
      const ushort_t* gv = vth + (size_t)(rr + lrow) * S_ + (ch) * 64 + lc16 * 8; \
      __builtin_amdgcn_global_load_lds((gas_ptr)gv, (las_ptr)(&vtt[bufi][rr * 64]), 16, 0, 0); \
    }                                                                          \
  }

#define LBLOAD(dst, ch)                                                        \
  {                                                                            \
    _Pragma("unroll")                                                          \
    for (int ss = 0; ss < 4; ++ss)                                             \
      dst[ss] = *reinterpret_cast<const float4*>(lbh + (ch) * 64 + ss * 16 + 4 * g); \
  }

// One 64-key chunk. WAITX completes S(CH); LBC holds lb(CH) (in flight;
// compiler inserts its own counted vmcnt before first use).
#define CHUNK(CH, BUF, LBC, LBN, DO_LB, DO_S, WAITX)                           \
  {                                                                            \
    WAITX;                                                                     \
    __builtin_amdgcn_s_barrier();                                              \
    __builtin_amdgcn_sched_barrier(0);                                         \
    uint_t pw[8];                                                              \
    _Pragma("unroll")                                                          \
    for (int ss = 0; ss < 4; ++ss) {                                           \
      const ushort_t* ktb = &kt[BUF][(ss * 16 + c) * 64];                      \
      b8 ak0 = *reinterpret_cast<const b8*>(ktb + (g ^ (c & 7)) * 8);          \
      b8 ak1 = *reinterpret_cast<const b8*>(ktb + ((4 + g) ^ (c & 7)) * 8);    \
      __builtin_amdgcn_s_setprio(1);                                           \
      f4 s0 = __builtin_amdgcn_mfma_f32_16x16x32_bf16(ak0, qfr[0], zero4, 0, 0, 0); \
      s0 = __builtin_amdgcn_mfma_f32_16x16x32_bf16(ak1, qfr[1], s0, 0, 0, 0);  \
      __builtin_amdgcn_s_setprio(0);                                           \
      float p0 = exp2f(fmaf(C1, s0[0], LBC[ss].x));                            \
      float p1 = exp2f(fmaf(C1, s0[1], LBC[ss].y));                            \
      float p2 = exp2f(fmaf(C1, s0[2], LBC[ss].z));                            \
      float p3 = exp2f(fmaf(C1, s0[3], LBC[ss].w));                            \
      rs += (p0 + p1) + (p2 + p3);                                             \
      asm("v_cvt_pk_bf16_f32 %0, %1, %2" : "=v"(pw[2 * ss])     : "v"(p0), "v"(p1)); \
      asm("v_cvt_pk_bf16_f32 %0, %1, %2" : "=v"(pw[2 * ss + 1]) : "v"(p2), "v"(p3)); \
    }                                                                          \
    __builtin_amdgcn_s_setprio(1);                                             \
    _Pragma("unroll")                                                          \
    for (int sst = 0; sst < 2; ++sst) {                                        \
      U4 pa;                                                                   \
      pa.u[0] = pw[4 * sst + 0]; pa.u[1] = pw[4 * sst + 1];                    \
      pa.u[2] = pw[4 * sst + 2]; pa.u[3] = pw[4 * sst + 3];                    \
      _Pragma("unroll")                                                        \
      for (int db = 0; db < 4; ++db) {                                         \
        b8 bv = *reinterpret_cast<const b8*>(                                  \
            &vtt[BUF][(db * 16 + c) * 64] + (((4 * sst + g) ^ (c & 7)) * 8));  \
        acc[db] = __builtin_amdgcn_mfma_f32_16x16x32_bf16(pa.v, bv, acc[db], 0, 0, 0); \
      }                                                                        \
    }                                                                          \
    __builtin_amdgcn_s_setprio(0);                                             \
    __builtin_amdgcn_sched_barrier(0);                                         \
    __builtin_amdgcn_s_barrier();                                              \
    if (DO_LB) { LBLOAD(LBN, (CH) + 1); }                                      \
    __builtin_amdgcn_sched_barrier(0);                                         \
    if (DO_S) { STAGE(BUF, (CH) + 2); }                                        \
  }

  // Prologue: S(0), LB(0), S(1) -> 12 vmem ops in flight.
  STAGE(0, 0);
  LBLOAD(lbA, 0);
  __builtin_amdgcn_sched_barrier(0);
  STAGE(1, 1);

  for (int ch = 0; ch < 28; ch += 2) {
    CHUNK(ch,     0, lbA, lbB, true, true, WAITV8);
    CHUNK(ch + 1, 1, lbB, lbA, true, true, WAITV8);
  }
  CHUNK(28, 0, lbA, lbB, true,  true,  WAITV8);   // LB(29), S(30)
  CHUNK(29, 1, lbB, lbA, true,  true,  WAITV8);   // LB(30), S(31)
  CHUNK(30, 0, lbA, lbB, true,  false, WAITV8);   // LB(31)
  CHUNK(31, 1, lbB, lbA, false, false, WAITV4);   // drain

#undef CHUNK
#undef STAGE
#undef LBLOAD
#undef WAITV8
#undef WAITV4

  // Z per q-row: lane (c,g) rs = partial for q-row c; reduce over g.
  rs += __shfl_xor(rs, 16);
  rs += __shfl_xor(rs, 32);
  if (g == 0) zb[w][c] = 1.f / (rs + epsr);
  __syncthreads();

  // out[n][qrow0 + 4g + r][hd][db*16 + c]
  const float4 z4 = *reinterpret_cast<const float4*>(&zb[w][4 * g]);
  const float zz[4] = {z4.x, z4.y, z4.z, z4.w};
  float* ob = out + (((size_t)n * L_ + qrow0 + 4 * g) * H_ + hd) * 64;
#pragma unroll
  for (int db = 0; db < 4; ++db) {
#pragma unroll
    for (int r = 0; r < 4; ++r) {
      ob[(size_t)r * (H_ * 64) + db * 16 + c] = acc[db][r] * zz[r];
    }
  }
}

extern "C" void kernel_launch(void* const* d_in, const int* in_sizes, int n_in,
                              void* d_out, int out_size, void* d_ws, size_t ws_size,
                              hipStream_t stream) {
  const float* q = (const float*)d_in[0];
  const float* k = (const float*)d_in[1];
  const float* v = (const float*)d_in[2];
  const float* mask = (const float*)d_in[3];
  float* out = (float*)d_out;

  char* ws = (char*)d_ws;
  ushort_t* kb = (ushort_t*)ws;
  ushort_t* vt = (ushort_t*)(ws + ((size_t)8 << 20));
  float* lbf = (float*)(ws + ((size_t)16 << 20));

  k_prep<<<dim3(2048), dim3(256), 0, stream>>>(k, kb, lbf, mask, v, vt);
  k_attn<<<dim3(1024), dim3(256), 0, stream>>>(q, kb, vt, lbf, out);
}

// Round 17
// 66.478 us; speedup vs baseline: 2.8692x; 1.1633x over previous
//
#include <hip/hip_runtime.h>
#include <stdint.h>

// RBF kernel attention, MI355X. N=4, L=S=2048, H=8, E=D=64.
// phi = exp(-(q^2+k^2-2qk)/16)*mask; out = (phi V)/(rowsum(phi)+1e-6)
// Factorized: p = exp2(fma(C1, qk, lb)), lb = -C2*k^2 + log2(mask); q^2
// cancels in Z; epilogue eps' = 1e-6*exp2(C2*q^2).
// Round-17 = r14/r16 champion with ONE change: exp2f libcall (OCML, has
// denormal-fixup VALU overhead) -> __builtin_amdgcn_exp2f (bare v_exp_f32).
// Numerically safe: denormal-flushed p < 1e-38 is below bf16 phi quantum;
// -inf -> 0 handled by HW.
// Structure: k_attn 16 q-rows/wave, 4-wave blocks, grid 1024 (4 blocks/CU,
// 4 waves/SIMD), 64-key chunks, K+V dbuf LDS via global_load_lds
// (pre-swizzled source), counted-vmcnt pipeline (vmcnt(8), never drained),
// swapped QK^T + zero-shuffle PV (V^T sigma-permuted), XCD swizzle;
// k_prep merged prepass.
//
// ws layout:
//   [0,8MB)    K bf16   [n][h][s][64]
//   [8,16MB)   V^T bf16 [n][h][d][sigma(s)]
//   [16MB,+256KB) lbf f32 [n][h][s]

#define N_ 4
#define L_ 2048
#define H_ 8
#define S_ 2048

#define C1 0.18033688f   // log2(e)/8
#define C2 0.09016844f   // log2(e)/16

typedef unsigned short ushort_t;
typedef unsigned int uint_t;
typedef __bf16 b8 __attribute__((ext_vector_type(8)));
typedef float f4 __attribute__((ext_vector_type(4)));
typedef const __attribute__((address_space(1))) uint32_t* gas_ptr;
typedef __attribute__((address_space(3))) uint32_t* las_ptr;

static __device__ __forceinline__ ushort_t f2bf(float x) {
  uint32_t u = __float_as_uint(x);
  u += 0x7fffu + ((u >> 16) & 1u);   // RNE
  return (ushort_t)(u >> 16);
}

// Merged prepass. Blocks 0-1023: K fp32 -> bf16 + lbf. Blocks 1024-2047:
// V [n][s][h][64] fp32 -> V^T bf16 [n][h][d][sigma(s)] via LDS tile.
// sigma: stored position p holds source s=(p&32)+((p>>2)&1)*16+((p>>3)&3)*4+(p&3)
// so the PV B-fragment (keys 32sst+4g+16(b>>2)+(b&3)) is one contiguous b128.
__global__ __launch_bounds__(256) void k_prep(const float* __restrict__ ksrc,
                                              ushort_t* __restrict__ kdst,
                                              float* __restrict__ lbf,
                                              const float* __restrict__ mask,
                                              const float* __restrict__ v,
                                              ushort_t* __restrict__ vt) {
  __shared__ __align__(16) ushort_t tile[64][68];
  if (blockIdx.x < 1024) {
    // ---- K convert + lb ----
    int t = blockIdx.x * 256 + threadIdx.x;
    int row = t >> 2, part = t & 3;
    const float4* p = reinterpret_cast<const float4*>(ksrc + (size_t)row * 64 + part * 16);
    uint_t o[8];
    float s = 0.f;
#pragma unroll
    for (int i = 0; i < 4; ++i) {
      float4 vv = p[i];
      s += vv.x * vv.x + vv.y * vv.y + vv.z * vv.z + vv.w * vv.w;
      o[2 * i]     = (uint_t)f2bf(vv.x) | ((uint_t)f2bf(vv.y) << 16);
      o[2 * i + 1] = (uint_t)f2bf(vv.z) | ((uint_t)f2bf(vv.w) << 16);
    }
    uint4* dp = reinterpret_cast<uint4*>(kdst + (size_t)row * 64 + part * 16);
    dp[0] = make_uint4(o[0], o[1], o[2], o[3]);
    dp[1] = make_uint4(o[4], o[5], o[6], o[7]);
    s += __shfl_xor(s, 1);
    s += __shfl_xor(s, 2);
    if (part == 0) {
      int n = row >> 14;          // / (H*S)
      int sidx = row & (S_ - 1);  // % S
      float m = mask[n * S_ + sidx];
      lbf[row] = -C2 * s + __log2f(m);   // m=0 -> -inf -> p=0
    }
  } else {
    // ---- V transpose ----
    const int vb = blockIdx.x - 1024;
    const int sc = vb & 31;          // 32 s-chunks
    const int h = (vb >> 5) & 7;
    const int n = vb >> 8;
    const int t = threadIdx.x;
    const int sl = t >> 4;
    const int dp = (t & 15) * 4;
#pragma unroll
    for (int i = 0; i < 4; ++i) {
      int s = sc * 64 + i * 16 + sl;
      float4 val = *reinterpret_cast<const float4*>(
          v + (((size_t)n * S_ + s) * H_ + h) * 64 + dp);
      tile[dp + 0][i * 16 + sl] = f2bf(val.x);
      tile[dp + 1][i * 16 + sl] = f2bf(val.y);
      tile[dp + 2][i * 16 + sl] = f2bf(val.z);
      tile[dp + 3][i * 16 + sl] = f2bf(val.w);
    }
    __syncthreads();
    const int d = t >> 2, sp = (t & 3) * 16;
    uint_t o[8];
#pragma unroll
    for (int i = 0; i < 8; ++i) {
      const int p0 = sp + 2 * i, p1 = p0 + 1;
      const int s0 = (p0 & 32) + (((p0 >> 2) & 1) << 4) + (((p0 >> 3) & 3) << 2) + (p0 & 3);
      const int s1 = (p1 & 32) + (((p1 >> 2) & 1) << 4) + (((p1 >> 3) & 3) << 2) + (p1 & 3);
      o[i] = (uint_t)tile[d][s0] | ((uint_t)tile[d][s1] << 16);
    }
    size_t base = ((size_t)(n * H_ + h) * 64 + d) * S_ + sc * 64 + sp;
    uint4* w = reinterpret_cast<uint4*>(vt + base);
    w[0] = make_uint4(o[0], o[1], o[2], o[3]);
    w[1] = make_uint4(o[4], o[5], o[6], o[7]);
  }
}

// Main kernel (champion): 4 waves/block, wave owns 16 q-rows, chunk = 64
// keys, counted-vmcnt double-buffered pipeline.
__global__ __launch_bounds__(256, 4) void k_attn(
    const float* __restrict__ qf32, const ushort_t* __restrict__ kb,
    const ushort_t* __restrict__ vt, const float* __restrict__ lbf,
    float* __restrict__ out) {
  __shared__ __align__(16) ushort_t kt[2][64 * 64];
  __shared__ __align__(16) ushort_t vtt[2][64 * 64];
  __shared__ __align__(16) float zb[4][16];

  const int lane = threadIdx.x & 63;
  const int w = threadIdx.x >> 6;   // 0..3
  const int bid = blockIdx.x;
  const int swz = (bid & 7) * 128 + (bid >> 3);  // XCD-chunked (1024 % 8 == 0)
  const int qt = swz & 31;
  const int hd = (swz >> 5) & 7;
  const int n = swz >> 8;
  const int nh = n * H_ + hd;
  const int c = lane & 15;
  const int g = lane >> 4;
  const int qrow0 = qt * 64 + w * 16;

  union U4 { uint_t u[4]; b8 v; };

  // ---- Q prologue: fp32 -> bf16 frags + q^2 -> eps' ----
  const float* qsrc = qf32 + ((size_t)nh * L_ + qrow0) * 64;
  b8 qfr[2];
  float epsr;
  {
    const float* rp = qsrc + (size_t)c * 64 + g * 8;
    float s = 0.f;
#pragma unroll
    for (int es = 0; es < 2; ++es) {
      float4 v0 = *reinterpret_cast<const float4*>(rp + es * 32);
      float4 v1 = *reinterpret_cast<const float4*>(rp + es * 32 + 4);
      s += v0.x * v0.x + v0.y * v0.y + v0.z * v0.z + v0.w * v0.w
         + v1.x * v1.x + v1.y * v1.y + v1.z * v1.z + v1.w * v1.w;
      U4 tq;
      tq.u[0] = (uint_t)f2bf(v0.x) | ((uint_t)f2bf(v0.y) << 16);
      tq.u[1] = (uint_t)f2bf(v0.z) | ((uint_t)f2bf(v0.w) << 16);
      tq.u[2] = (uint_t)f2bf(v1.x) | ((uint_t)f2bf(v1.y) << 16);
      tq.u[3] = (uint_t)f2bf(v1.z) | ((uint_t)f2bf(v1.w) << 16);
      qfr[es] = tq.v;
    }
    s += __shfl_xor(s, 16);
    s += __shfl_xor(s, 32);
    epsr = 1e-6f * __builtin_amdgcn_exp2f(C2 * s);   // eps' for q-row c
  }

  const ushort_t* kbh = kb + (size_t)nh * S_ * 64;
  const ushort_t* vth = vt + (size_t)nh * 64 * S_;
  const float* lbh = lbf + (size_t)nh * S_;

  f4 zero4 = {0.f, 0.f, 0.f, 0.f};
  f4 acc[4] = {zero4, zero4, zero4, zero4};
  float rs = 0.f;

  const int lrow = lane >> 3;          // staging row in 8-row piece
  const int lc16 = (lane & 7) ^ lrow;  // pre-swizzled global 16B slot

  float4 lbA[4], lbB[4];

#define WAITV8 asm volatile("s_waitcnt vmcnt(8)" ::: "memory")
#define WAITV4 asm volatile("s_waitcnt vmcnt(4)" ::: "memory")

#define STAGE(bufi, ch)                                                        \
  {                                                                            \
    _Pragma("unroll")                                                          \
    for (int t2 = 0; t2 < 2; ++t2) {                                           \
      const int rr = w * 16 + t2 * 8;                                          \
      const ushort_t* gk = kbh + ((size_t)(ch) * 64 + rr + lrow) * 64 + lc16 * 8; \
      __builtin_amdgcn_global_load_lds((gas_ptr)gk, (las_ptr)(&kt[bufi][rr * 64]), 16, 0, 0); \
      const ushort_t* gv = vth + (size_t)(rr + lrow) * S_ + (ch) * 64 + lc16 * 8; \
      __builtin_amdgcn_global_load_lds((gas_ptr)gv, (las_ptr)(&vtt[bufi][rr * 64]), 16, 0, 0); \
    }                                                                          \
  }

#define LBLOAD(dst, ch)                                                        \
  {                                                                            \
    _Pragma("unroll")                                                          \
    for (int ss = 0; ss < 4; ++ss)                                             \
      dst[ss] = *reinterpret_cast<const float4*>(lbh + (ch) * 64 + ss * 16 + 4 * g); \
  }

// One 64-key chunk. WAITX completes S(CH); LBC holds lb(CH) (in flight;
// compiler inserts its own counted vmcnt before first use).
#define CHUNK(CH, BUF, LBC, LBN, DO_LB, DO_S, WAITX)                           \
  {                                                                            \
    WAITX;                                                                     \
    __builtin_amdgcn_s_barrier();                                              \
    __builtin_amdgcn_sched_barrier(0);                                         \
    uint_t pw[8];                                                              \
    _Pragma("unroll")                                                          \
    for (int ss = 0; ss < 4; ++ss) {                                           \
      const ushort_t* ktb = &kt[BUF][(ss * 16 + c) * 64];                      \
      b8 ak0 = *reinterpret_cast<const b8*>(ktb + (g ^ (c & 7)) * 8);          \
      b8 ak1 = *reinterpret_cast<const b8*>(ktb + ((4 + g) ^ (c & 7)) * 8);    \
      __builtin_amdgcn_s_setprio(1);                                           \
      f4 s0 = __builtin_amdgcn_mfma_f32_16x16x32_bf16(ak0, qfr[0], zero4, 0, 0, 0); \
      s0 = __builtin_amdgcn_mfma_f32_16x16x32_bf16(ak1, qfr[1], s0, 0, 0, 0);  \
      __builtin_amdgcn_s_setprio(0);                                           \
      float p0 = __builtin_amdgcn_exp2f(fmaf(C1, s0[0], LBC[ss].x));           \
      float p1 = __builtin_amdgcn_exp2f(fmaf(C1, s0[1], LBC[ss].y));           \
      float p2 = __builtin_amdgcn_exp2f(fmaf(C1, s0[2], LBC[ss].z));           \
      float p3 = __builtin_amdgcn_exp2f(fmaf(C1, s0[3], LBC[ss].w));           \
      rs += (p0 + p1) + (p2 + p3);                                             \
      asm("v_cvt_pk_bf16_f32 %0, %1, %2" : "=v"(pw[2 * ss])     : "v"(p0), "v"(p1)); \
      asm("v_cvt_pk_bf16_f32 %0, %1, %2" : "=v"(pw[2 * ss + 1]) : "v"(p2), "v"(p3)); \
    }                                                                          \
    __builtin_amdgcn_s_setprio(1);                                             \
    _Pragma("unroll")                                                          \
    for (int sst = 0; sst < 2; ++sst) {                                        \
      U4 pa;                                                                   \
      pa.u[0] = pw[4 * sst + 0]; pa.u[1] = pw[4 * sst + 1];                    \
      pa.u[2] = pw[4 * sst + 2]; pa.u[3] = pw[4 * sst + 3];                    \
      _Pragma("unroll")                                                        \
      for (int db = 0; db < 4; ++db) {                                         \
        b8 bv = *reinterpret_cast<const b8*>(                                  \
            &vtt[BUF][(db * 16 + c) * 64] + (((4 * sst + g) ^ (c & 7)) * 8));  \
        acc[db] = __builtin_amdgcn_mfma_f32_16x16x32_bf16(pa.v, bv, acc[db], 0, 0, 0); \
      }                                                                        \
    }                                                                          \
    __builtin_amdgcn_s_setprio(0);                                             \
    __builtin_amdgcn_sched_barrier(0);                                         \
    __builtin_amdgcn_s_barrier();                                              \
    if (DO_LB) { LBLOAD(LBN, (CH) + 1); }                                      \
    __builtin_amdgcn_sched_barrier(0);                                         \
    if (DO_S) { STAGE(BUF, (CH) + 2); }                                        \
  }

  // Prologue: S(0), LB(0), S(1) -> 12 vmem ops in flight.
  STAGE(0, 0);
  LBLOAD(lbA, 0);
  __builtin_amdgcn_sched_barrier(0);
  STAGE(1, 1);

  for (int ch = 0; ch < 28; ch += 2) {
    CHUNK(ch,     0, lbA, lbB, true, true, WAITV8);
    CHUNK(ch + 1, 1, lbB, lbA, true, true, WAITV8);
  }
  CHUNK(28, 0, lbA, lbB, true,  true,  WAITV8);   // LB(29), S(30)
  CHUNK(29, 1, lbB, lbA, true,  true,  WAITV8);   // LB(30), S(31)
  CHUNK(30, 0, lbA, lbB, true,  false, WAITV8);   // LB(31)
  CHUNK(31, 1, lbB, lbA, false, false, WAITV4);   // drain

#undef CHUNK
#undef STAGE
#undef LBLOAD
#undef WAITV8
#undef WAITV4

  // Z per q-row: lane (c,g) rs = partial for q-row c; reduce over g.
  rs += __shfl_xor(rs, 16);
  rs += __shfl_xor(rs, 32);
  if (g == 0) zb[w][c] = 1.f / (rs + epsr);
  __syncthreads();

  // out[n][qrow0 + 4g + r][hd][db*16 + c]
  const float4 z4 = *reinterpret_cast<const float4*>(&zb[w][4 * g]);
  const float zz[4] = {z4.x, z4.y, z4.z, z4.w};
  float* ob = out + (((size_t)n * L_ + qrow0 + 4 * g) * H_ + hd) * 64;
#pragma unroll
  for (int db = 0; db < 4; ++db) {
#pragma unroll
    for (int r = 0; r < 4; ++r) {
      ob[(size_t)r * (H_ * 64) + db * 16 + c] = acc[db][r] * zz[r];
    }
  }
}

extern "C" void kernel_launch(void* const* d_in, const int* in_sizes, int n_in,
                              void* d_out, int out_size, void* d_ws, size_t ws_size,
                              hipStream_t stream) {
  const float* q = (const float*)d_in[0];
  const float* k = (const float*)d_in[1];
  const float* v = (const float*)d_in[2];
  const float* mask = (const float*)d_in[3];
  float* out = (float*)d_out;

  char* ws = (char*)d_ws;
  ushort_t* kb = (ushort_t*)ws;
  ushort_t* vt = (ushort_t*)(ws + ((size_t)8 << 20));
  float* lbf = (float*)(ws + ((size_t)16 << 20));

  k_prep<<<dim3(2048), dim3(256), 0, stream>>>(k, kb, lbf, mask, v, vt);
  k_attn<<<dim3(1024), dim3(256), 0, stream>>>(q, kb, vt, lbf, out);
}